// Round 5
// baseline (1026.018 us; speedup 1.0000x reference)
//
#include <hip/hip_runtime.h>
#include <math.h>

#define NB 256
#define NS 512
#define ND 256
#define NL 4
#define NITERS 10
#define DD (ND*ND)      // 65536

// ---------------------------------------------------------------------------
// K1: partial[(4b+q)][d] = sum over 128 s of emb[ids[b,s]][d] + pos[s][d]
// ---------------------------------------------------------------------------
__global__ __launch_bounds__(256) void k_pool1(const int* __restrict__ ids,
                                               const float* __restrict__ emb,
                                               const float* __restrict__ pos,
                                               float* __restrict__ partial) {
    const int bid = blockIdx.x;
    const int b = bid >> 2, q = bid & 3;
    const int t = threadIdx.x;
    __shared__ int sid[128];
    if (t < 128) sid[t] = ids[b * NS + q * 128 + t];
    __syncthreads();
    float acc = 0.f;
#pragma unroll 8
    for (int s = 0; s < 128; ++s)
        acc += emb[(size_t)sid[s] * ND + t] + pos[(q * 128 + s) * ND + t];
    partial[bid * ND + t] = acc;
}

// ---------------------------------------------------------------------------
// k_prep: precompute combined matrices (stored TRANSPOSED [k][d] for
// coalesced apply), transposed init weights, head fold-ins, const vectors.
//   CM slots (each DD floats): 0:G0 1:H0 3:U1t 4:G1 5:H1 6:U2t 7:G2 8:H2
//                              9:U3t 10:G3      (G=0.5U-UP, H=-0.5UP')
//   rc0[row][d] = (U0 . pooled_row)[d]
//   KSt[f][e] = sum_k sw[k][f]*kw[k][e]  (sqk = KSt^T-apply(refined)+ksb)
// ---------------------------------------------------------------------------
__global__ __launch_bounds__(256) void k_prep(
    const float* __restrict__ pred_w, const float* __restrict__ pred_b,
    const float* __restrict__ upd_w,  const float* __restrict__ upd_b,
    const float* __restrict__ init_w,
    const float* __restrict__ sw, const float* __restrict__ sb,
    const float* __restrict__ ew, const float* __restrict__ eb,
    const float* __restrict__ kw, const float* __restrict__ kb,
    const float* __restrict__ w1,
    const float* __restrict__ partial,
    float* __restrict__ CM, float* __restrict__ CMI,
    float* __restrict__ KSt, float* __restrict__ KEt, float* __restrict__ W1t,
    float* __restrict__ cvec, float* __restrict__ rc0,
    float* __restrict__ vsk, float* __restrict__ vse,
    float* __restrict__ ksb, float* __restrict__ keb, float* __restrict__ scal)
{
    const int bid = blockIdx.x;
    const int t = threadIdx.x;

    if (bid < 576 || (bid >= 1056 && bid < 1120)) {
        // -------- GEMM blocks: OUT[i][j] = alpha*sum_e A(e,i)*B(j|e) + tau*T[j][i]
        int id, tile;
        if (bid < 576) { id = bid >> 6; tile = bid & 63; }
        else           { id = 9;        tile = bid - 1056; }
        const float* Asrc = nullptr; const float* Bsrc = nullptr;
        float alpha = 1.f, tau = 0.f; float* outp = nullptr;
        bool bT = false, aPool = false;
        switch (id) {
            case 0: Asrc = pred_w;        Bsrc = upd_w;        alpha=-1.f;  tau=0.5f; outp = CM + 0*(size_t)DD; break;
            case 1: Asrc = pred_w + DD;   Bsrc = upd_w;        alpha=-0.5f;           outp = CM + 1*(size_t)DD; break;
            case 2: Asrc = pred_w + DD;   Bsrc = upd_w + DD;   alpha=-1.f;  tau=0.5f; outp = CM + 4*(size_t)DD; break;
            case 3: Asrc = pred_w + 2*DD; Bsrc = upd_w + DD;   alpha=-0.5f;           outp = CM + 5*(size_t)DD; break;
            case 4: Asrc = pred_w + 2*DD; Bsrc = upd_w + 2*DD; alpha=-1.f;  tau=0.5f; outp = CM + 7*(size_t)DD; break;
            case 5: Asrc = pred_w + 3*DD; Bsrc = upd_w + 2*DD; alpha=-0.5f;           outp = CM + 8*(size_t)DD; break;
            case 6: Asrc = pred_w + 3*DD; Bsrc = upd_w + 3*DD; alpha=-1.f;            outp = CM + 10*(size_t)DD; break;
            case 7: Asrc = sw; Bsrc = kw; bT = true; outp = KSt; break;
            case 8: Asrc = ew; Bsrc = kw; bT = true; outp = KEt; break;
            default: Bsrc = upd_w; aPool = true; outp = rc0; break; // rc0: A=pooled(from partial), B=U0
        }
        const float* Tsrc = (tau != 0.f) ? Bsrc : nullptr;
        const int i0 = (tile >> 3) * 32, j0 = (tile & 7) * 32;
        __shared__ float As[32 * 33];
        __shared__ float Bs[32 * 33];
        const int tx = t & 15, ty = t >> 4;
        float a00 = 0.f, a01 = 0.f, a10 = 0.f, a11 = 0.f;
        for (int e0 = 0; e0 < 256; e0 += 32) {
            __syncthreads();
            if (!aPool) { // T-form: As[e][i] = Asrc[e][i] (lanes i coalesced)
                const int ii = t & 31, e8 = t >> 5;
#pragma unroll
                for (int p = 0; p < 4; ++p) {
                    int ee = e8 + 8 * p;
                    As[ee * 33 + ii] = Asrc[(size_t)(e0 + ee) * 256 + i0 + ii];
                }
            } else {      // pooled rows from partial (lanes e coalesced)
                const int ee = t & 31, i8 = t >> 5;
#pragma unroll
                for (int p = 0; p < 4; ++p) {
                    int ii = i8 + 8 * p;
                    const float* pp = partial + (size_t)(i0 + ii) * 4 * 256 + e0 + ee;
                    As[ee * 33 + ii] = (pp[0] + pp[256] + pp[512] + pp[768]) * (1.f / 512.f);
                }
            }
            if (!bT) {    // N-form: Bs[e][j] = Bsrc[j][e] (lanes e coalesced)
                const int ee = t & 31, j8 = t >> 5;
#pragma unroll
                for (int p = 0; p < 4; ++p) {
                    int jj = j8 + 8 * p;
                    Bs[ee * 33 + jj] = Bsrc[(size_t)(j0 + jj) * 256 + e0 + ee];
                }
            } else {      // T-form: Bs[e][j] = Bsrc[e][j] (lanes j coalesced)
                const int jj = t & 31, e8 = t >> 5;
#pragma unroll
                for (int p = 0; p < 4; ++p) {
                    int ee = e8 + 8 * p;
                    Bs[ee * 33 + jj] = Bsrc[(size_t)(e0 + ee) * 256 + j0 + jj];
                }
            }
            __syncthreads();
#pragma unroll
            for (int e = 0; e < 32; ++e) {
                float va0 = As[e * 33 + 2 * ty], va1 = As[e * 33 + 2 * ty + 1];
                float vb0 = Bs[e * 33 + 2 * tx], vb1 = Bs[e * 33 + 2 * tx + 1];
                a00 += va0 * vb0; a01 += va0 * vb1;
                a10 += va1 * vb0; a11 += va1 * vb1;
            }
        }
        float t00 = 0.f, t01 = 0.f, t10 = 0.f, t11 = 0.f;
        if (Tsrc) {
            t00 = Tsrc[(size_t)(j0 + 2 * tx) * 256 + i0 + 2 * ty];
            t01 = Tsrc[(size_t)(j0 + 2 * tx + 1) * 256 + i0 + 2 * ty];
            t10 = Tsrc[(size_t)(j0 + 2 * tx) * 256 + i0 + 2 * ty + 1];
            t11 = Tsrc[(size_t)(j0 + 2 * tx + 1) * 256 + i0 + 2 * ty + 1];
        }
        outp[(size_t)(i0 + 2 * ty) * 256 + j0 + 2 * tx]         = alpha * a00 + tau * t00;
        outp[(size_t)(i0 + 2 * ty) * 256 + j0 + 2 * tx + 1]     = alpha * a01 + tau * t01;
        outp[(size_t)(i0 + 2 * ty + 1) * 256 + j0 + 2 * tx]     = alpha * a10 + tau * t10;
        outp[(size_t)(i0 + 2 * ty + 1) * 256 + j0 + 2 * tx + 1] = alpha * a11 + tau * t11;
        return;
    }

    if (bid < 1024) {
        // -------- 256x256 transposes: 7 matrices (U1,U2,U3 -> CM 3/6/9; IW0-3 -> CMI)
        const int tid = bid - 576;
        const int m = tid >> 6, tile = tid & 63;
        const float* src; float* dst;
        if (m < 3) { src = upd_w + (size_t)(m + 1) * DD; dst = CM + (size_t)(3 + 3 * m) * DD; }
        else       { src = init_w + (size_t)(m - 3) * DD; dst = CMI + (size_t)(m - 3) * DD; }
        const int r0 = (tile >> 3) * 32, c0 = (tile & 7) * 32;
        __shared__ float T[32 * 33];
        const int cc = t & 31, r8 = t >> 5;
#pragma unroll
        for (int p = 0; p < 4; ++p) {
            int rr = r8 + 8 * p;
            T[rr * 33 + cc] = src[(size_t)(r0 + rr) * 256 + c0 + cc];
        }
        __syncthreads();
#pragma unroll
        for (int p = 0; p < 4; ++p) {
            int rr = r8 + 8 * p;
            dst[(size_t)(c0 + rr) * 256 + r0 + cc] = T[cc * 33 + rr];
        }
        return;
    }

    if (bid < 1056) {
        // -------- w1 [128][256] -> W1t [256][128]
        const int tile = bid - 1024;              // 0..31: 8 e-tiles x 4 j-tiles
        const int e0 = (tile >> 2) * 32, j0 = (tile & 3) * 32;
        __shared__ float T[32 * 33];
        const int cc = t & 31, r8 = t >> 5;
#pragma unroll
        for (int p = 0; p < 4; ++p) {
            int jj = r8 + 8 * p;
            T[jj * 33 + cc] = w1[(size_t)(j0 + jj) * 256 + e0 + cc];
        }
        __syncthreads();
#pragma unroll
        for (int p = 0; p < 4; ++p) {
            int ee = r8 + 8 * p;
            W1t[(size_t)(e0 + ee) * 128 + j0 + cc] = T[cc * 33 + ee];
        }
        return;
    }

    // -------- vector blocks
    const int vb = bid - 1120;
    if (vb < 4) { // c_l[d] = ub_l[d] - sum_k U_l[d][k]*(pb_l[k] + 0.5*pb_{l+1}[k])
        const int l = vb;
        __shared__ float v[256];
        v[t] = (l < 3) ? pred_b[l * 256 + t] + 0.5f * pred_b[(l + 1) * 256 + t]
                       : pred_b[3 * 256 + t];
        __syncthreads();
        const float* U = upd_w + (size_t)l * DD + (size_t)t * 256;
        float acc = 0.f;
#pragma unroll 8
        for (int k = 0; k < 256; k += 4) {
            float4 u = *(const float4*)&U[k];
            acc += u.x * v[k] + u.y * v[k + 1] + u.z * v[k + 2] + u.w * v[k + 3];
        }
        cvec[l * 256 + t] = upd_b[l * 256 + t] - acc;
        return;
    }
    { // vb==4: vsk/ksb from sw/sb; vb==5: vse/keb from ew/eb
        const float* W = (vb == 4) ? sw : ew;
        const float* bb = (vb == 4) ? sb : eb;
        float* vout = (vb == 4) ? vsk : vse;
        float* bout = (vb == 4) ? ksb : keb;
        __shared__ float kbv[256], bbv[256], red[256];
        kbv[t] = kb[t]; bbv[t] = bb[t];
        __syncthreads();
        float a1 = 0.f, a2 = 0.f;
#pragma unroll 4
        for (int k = 0; k < 256; ++k) {
            a1 += W[(size_t)k * 256 + t] * kbv[k];
            a2 += kw[(size_t)k * 256 + t] * bbv[k];
        }
        vout[t] = a1; bout[t] = a2;
        red[t] = kbv[t] * bbv[t];
        __syncthreads();
        for (int s = 128; s > 0; s >>= 1) {
            if (t < s) red[t] += red[t + s];
            __syncthreads();
        }
        if (t == 0) scal[vb - 4] = red[0];
        return;
    }
}

// ---------------------------------------------------------------------------
// k_init: per-row init chain using transposed init weights (coalesced).
// ---------------------------------------------------------------------------
__global__ __launch_bounds__(256) void k_init(const float* __restrict__ partial,
                                              const float* __restrict__ CMI,
                                              const float* __restrict__ init_b,
                                              float* __restrict__ rA,
                                              float* __restrict__ ff)
{
    const int row = blockIdx.x, t = threadIdx.x;
    __shared__ float xs[256];
    {
        const float* p = partial + (size_t)row * 4 * 256 + t;
        xs[t] = (p[0] + p[256] + p[512] + p[768]) * (1.f / 512.f);
    }
    float* rrow = rA + (size_t)row * 1024;
    for (int il = 0; il < 4; ++il) {
        __syncthreads();
        const float* M = CMI + (size_t)il * DD + t;
        float a0 = 0.f, a1 = 0.f, a2 = 0.f, a3 = 0.f;
#pragma unroll 8
        for (int k = 0; k < 256; k += 4) {
            float4 xv = *(const float4*)&xs[k];
            a0 += M[(size_t)(k + 0) * 256] * xv.x;
            a1 += M[(size_t)(k + 1) * 256] * xv.y;
            a2 += M[(size_t)(k + 2) * 256] * xv.z;
            a3 += M[(size_t)(k + 3) * 256] * xv.w;
        }
        float vx = tanhf(a0 + a1 + a2 + a3 + init_b[il * 256 + t]);
        __syncthreads();
        xs[t] = vx;
        rrow[il * 256 + t] = vx;
        if (il == 3) ff[(size_t)row * 256 + t] = vx;
    }
}

// ---------------------------------------------------------------------------
// k_stage: one refinement iteration as LDS-staged tiled GEMM.
//  z_l = sum_j CM[l*3+j]^T-apply . r_{slo+j} + cvec_l (+rc0 for l=0)
//  r_new = r + 0.1*tanh(z)
// grid 512 = 16 rowtiles(16 rows) x (4 layers x 8 coltiles of 32); block 256.
// Per 64-k chunk: As[16][64] (pad 68) + Bs[64][32] (pad 33) staged coalesced;
// register prefetch of chunk c+1 issued before compute (T14 split).
// ---------------------------------------------------------------------------
__global__ __launch_bounds__(256) void k_stage(const float* __restrict__ rcur,
                                               const float* __restrict__ CM,
                                               const float* __restrict__ cvec,
                                               const float* __restrict__ rc0,
                                               float* __restrict__ rnxt)
{
    __shared__ float As[16 * 68];
    __shared__ float Bs[64 * 33];
    const int bid = blockIdx.x;
    const int t = threadIdx.x;
    const int rowtile = bid >> 5, ct = bid & 31;
    const int l = ct >> 3, d0 = (ct & 7) * 32;
    const int slo = (l == 0) ? 0 : (l - 1);
    const int shi = (l == 3) ? 3 : (l + 1);
    const int KK = (shi - slo + 1) * 256;
    const int r0 = rowtile * 16;

    // staging indices
    const int arow = t >> 4, ak4 = (t & 15) * 4;      // A: row, k-quad
    const int bkk = t >> 3, bc4 = (t & 7) * 4;        // B: k-row, col-quad
    // compute indices
    const int ty = t >> 4, tx = t & 15;               // row, col-pair

    const float* aBase = rcur + (size_t)(r0 + arow) * 1024 + slo * 256;
    const int slotBase = l * 3;

    // prefetch chunk 0
    float4 pa = *(const float4*)&aBase[ak4];
    float4 pb0, pb1;
    {
        const float* Bsrc = CM + (size_t)slotBase * DD;
        pb0 = *(const float4*)&Bsrc[(size_t)bkk * 256 + d0 + bc4];
        pb1 = *(const float4*)&Bsrc[(size_t)(bkk + 32) * 256 + d0 + bc4];
    }

    float acc0a = 0.f, acc1a = 0.f, acc0b = 0.f, acc1b = 0.f;

    for (int c = 0; c < KK; c += 64) {
        // write staged chunk
        *(float4*)&As[arow * 68 + ak4] = pa;
        *(float4*)&Bs[bkk * 33 + bc4] = pb0;
        *(float4*)&Bs[(bkk + 32) * 33 + bc4] = pb1;
        __syncthreads();
        // prefetch next chunk (independent of LDS)
        const int cn = c + 64;
        if (cn < KK) {
            pa = *(const float4*)&aBase[cn + ak4];
            const int jblk = cn >> 8, kin = cn & 255;
            const float* Bsrc = CM + (size_t)(slotBase + jblk) * DD;
            pb0 = *(const float4*)&Bsrc[(size_t)(kin + bkk) * 256 + d0 + bc4];
            pb1 = *(const float4*)&Bsrc[(size_t)(kin + bkk + 32) * 256 + d0 + bc4];
        }
        // compute
        const float* Ap = &As[ty * 68];
        const float* Bp = &Bs[2 * tx];
#pragma unroll
        for (int kk = 0; kk < 64; kk += 8) {
            float4 av0 = *(const float4*)&Ap[kk];
            float4 av1 = *(const float4*)&Ap[kk + 4];
            float2 b0 = *(const float2*)&Bp[(kk + 0) * 33];
            float2 b1 = *(const float2*)&Bp[(kk + 1) * 33];
            float2 b2 = *(const float2*)&Bp[(kk + 2) * 33];
            float2 b3 = *(const float2*)&Bp[(kk + 3) * 33];
            float2 b4 = *(const float2*)&Bp[(kk + 4) * 33];
            float2 b5 = *(const float2*)&Bp[(kk + 5) * 33];
            float2 b6 = *(const float2*)&Bp[(kk + 6) * 33];
            float2 b7 = *(const float2*)&Bp[(kk + 7) * 33];
            acc0a += av0.x * b0.x + av0.y * b1.x + av0.z * b2.x + av0.w * b3.x;
            acc1a += av0.x * b0.y + av0.y * b1.y + av0.z * b2.y + av0.w * b3.y;
            acc0b += av1.x * b4.x + av1.y * b5.x + av1.z * b6.x + av1.w * b7.x;
            acc1b += av1.x * b4.y + av1.y * b5.y + av1.z * b6.y + av1.w * b7.y;
        }
        __syncthreads();
    }

    const int dcol = d0 + 2 * tx;
    const int grow = r0 + ty;
    float z0 = acc0a + acc0b + cvec[l * 256 + dcol];
    float z1 = acc1a + acc1b + cvec[l * 256 + dcol + 1];
    if (l == 0) {
        float2 rc = *(const float2*)&rc0[(size_t)grow * 256 + dcol];
        z0 += rc.x; z1 += rc.y;
    }
    float2 rold = *(const float2*)&rcur[(size_t)grow * 1024 + l * 256 + dcol];
    float2 outv = make_float2(rold.x + 0.1f * tanhf(z0), rold.y + 0.1f * tanhf(z1));
    *(float2*)&rnxt[(size_t)grow * 1024 + l * 256 + dcol] = outv;
}

// ---------------------------------------------------------------------------
// k_heads: per-row head computations (refined, sqk/eqk/sqb/eqb, answerable).
// ---------------------------------------------------------------------------
__global__ __launch_bounds__(256) void k_heads(const float* __restrict__ rA,
    const float* __restrict__ ff,
    const float* __restrict__ KSt, const float* __restrict__ KEt,
    const float* __restrict__ ksb, const float* __restrict__ keb,
    const float* __restrict__ vsk, const float* __restrict__ vse,
    const float* __restrict__ scal,
    const float* __restrict__ W1t, const float* __restrict__ b1,
    const float* __restrict__ w2, const float* __restrict__ b2,
    float* __restrict__ sqk, float* __restrict__ eqk,
    float* __restrict__ sqb, float* __restrict__ eqb,
    float* __restrict__ out)
{
    const int row = blockIdx.x, t = threadIdx.x;
    __shared__ float xs[256];
    __shared__ float red[256];
    __shared__ float hp[256];
    __shared__ float hs[128];
    xs[t] = rA[(size_t)row * 1024 + 768 + t] + ff[(size_t)row * 256 + t];
    __syncthreads();
    {
        float a0 = 0.f, a1 = 0.f, a2 = 0.f, a3 = 0.f;
        float e0 = 0.f, e1 = 0.f, e2 = 0.f, e3 = 0.f;
        const float* KS = KSt + t;
        const float* KE = KEt + t;
#pragma unroll 4
        for (int f = 0; f < 256; f += 4) {
            float4 xv = *(const float4*)&xs[f];
            a0 += KS[(size_t)(f + 0) * 256] * xv.x; a1 += KS[(size_t)(f + 1) * 256] * xv.y;
            a2 += KS[(size_t)(f + 2) * 256] * xv.z; a3 += KS[(size_t)(f + 3) * 256] * xv.w;
            e0 += KE[(size_t)(f + 0) * 256] * xv.x; e1 += KE[(size_t)(f + 1) * 256] * xv.y;
            e2 += KE[(size_t)(f + 2) * 256] * xv.z; e3 += KE[(size_t)(f + 3) * 256] * xv.w;
        }
        sqk[(size_t)row * 256 + t] = a0 + a1 + a2 + a3 + ksb[t];
        eqk[(size_t)row * 256 + t] = e0 + e1 + e2 + e3 + keb[t];
    }
    red[t] = vsk[t] * xs[t];
    __syncthreads();
    for (int s = 128; s > 0; s >>= 1) { if (t < s) red[t] += red[t + s]; __syncthreads(); }
    if (t == 0) sqb[row] = red[0] + scal[0];
    __syncthreads();
    red[t] = vse[t] * xs[t];
    __syncthreads();
    for (int s = 128; s > 0; s >>= 1) { if (t < s) red[t] += red[t + s]; __syncthreads(); }
    if (t == 0) eqb[row] = red[0] + scal[1];
    __syncthreads();
    {
        const int j = t & 127, half = t >> 7;
        float a = 0.f;
        const float* W = W1t + (size_t)half * 128 * 128 + j;
        const float* xh = &xs[half * 128];
#pragma unroll 8
        for (int e = 0; e < 128; ++e) a += W[(size_t)e * 128] * xh[e];
        hp[half * 128 + j] = a;
    }
    __syncthreads();
    if (t < 128) {
        float x = hp[t] + hp[128 + t] + b1[t];
        hs[t] = 0.5f * x * (1.f + erff(x * 0.70710678118654752f));
    }
    __syncthreads();
    if (t < 128) { red[t] = hs[t] * w2[t]; red[128 + t] = hs[t] * w2[128 + t]; }
    __syncthreads();
    for (int s = 64; s > 0; s >>= 1) {
        if (t < s) red[t] += red[t + s];
        else if (t >= 128 && t < 128 + s) red[t] += red[t + s];
        __syncthreads();
    }
    if (t == 0)   out[2 * NB * NS + row * 2 + 0] = red[0] + b2[0];
    if (t == 128) out[2 * NB * NS + row * 2 + 1] = red[128] + b2[1];
}

// ---------------------------------------------------------------------------
// logits gather
// ---------------------------------------------------------------------------
__global__ __launch_bounds__(512) void k_logits(const int* __restrict__ ids,
                                                const float* __restrict__ emb,
                                                const float* __restrict__ pos,
                                                const float* __restrict__ sqk,
                                                const float* __restrict__ eqk,
                                                const float* __restrict__ sqb,
                                                const float* __restrict__ eqb,
                                                float* __restrict__ out) {
    const int bid = blockIdx.x;
    const int b = bid >> 2, q = bid & 3;
    const int t = threadIdx.x;
    __shared__ float sk[ND], ek[ND];
    __shared__ int sid[128];
    if (t < 256) sk[t] = sqk[b * ND + t];
    else ek[t - 256] = eqk[b * ND + t - 256];
    if (t < 128) sid[t] = ids[b * NS + q * 128 + t];
    __syncthreads();
    const int w = t >> 6, lane = t & 63;
    const float4 ks = *(const float4*)&sk[4 * lane];
    const float4 ke = *(const float4*)&ek[4 * lane];
    const float qbs = sqb[b], qbe = eqb[b];
    for (int si = w; si < 128; si += 8) {
        const int s = q * 128 + si;
        const int id = sid[si];
        const float4 e4 = *(const float4*)&emb[(size_t)id * ND + 4 * lane];
        const float4 p4 = *(const float4*)&pos[s * ND + 4 * lane];
        float vx = e4.x + p4.x, vy = e4.y + p4.y, vz = e4.z + p4.z, vw = e4.w + p4.w;
        float ds = vx * ks.x + vy * ks.y + vz * ks.z + vw * ks.w;
        float de = vx * ke.x + vy * ke.y + vz * ke.z + vw * ke.w;
#pragma unroll
        for (int off = 32; off >= 1; off >>= 1) {
            ds += __shfl_xor(ds, off);
            de += __shfl_xor(de, off);
        }
        if (lane == 0) {
            out[b * NS + s] = ds + qbs;
            out[NB * NS + b * NS + s] = de + qbe;
        }
    }
}

// ---------------------------------------------------------------------------
extern "C" void kernel_launch(void* const* d_in, const int* in_sizes, int n_in,
                              void* d_out, int out_size, void* d_ws, size_t ws_size,
                              hipStream_t stream) {
    const int*   ids    = (const int*)d_in[0];
    const float* emb    = (const float*)d_in[1];
    const float* pos    = (const float*)d_in[2];
    const float* init_w = (const float*)d_in[3];
    const float* init_b = (const float*)d_in[4];
    const float* pred_w = (const float*)d_in[5];
    const float* pred_b = (const float*)d_in[6];
    const float* upd_w  = (const float*)d_in[7];
    const float* upd_b  = (const float*)d_in[8];
    const float* sw     = (const float*)d_in[9];
    const float* sb     = (const float*)d_in[10];
    const float* ew     = (const float*)d_in[11];
    const float* eb     = (const float*)d_in[12];
    const float* kw     = (const float*)d_in[13];
    const float* kb     = (const float*)d_in[14];
    const float* w1     = (const float*)d_in[15];
    const float* b1     = (const float*)d_in[16];
    const float* w2     = (const float*)d_in[17];
    const float* b2     = (const float*)d_in[18];
    float* out = (float*)d_out;

    float* ws = (float*)d_ws;
    float* partial = ws;                 ws += 1024 * 256;
    float* rA      = ws;                 ws += 256 * 1024;
    float* rB      = ws;                 ws += 256 * 1024;
    float* ff      = ws;                 ws += 256 * 256;
    float* CM      = ws;                 ws += 12 * DD;
    float* CMI     = ws;                 ws += 4 * DD;
    float* KSt     = ws;                 ws += DD;
    float* KEt     = ws;                 ws += DD;
    float* W1t     = ws;                 ws += 256 * 128;
    float* cvec    = ws;                 ws += 4 * 256;
    float* rc0     = ws;                 ws += 256 * 256;
    float* vsk     = ws;                 ws += 256;
    float* vse     = ws;                 ws += 256;
    float* ksb     = ws;                 ws += 256;
    float* keb     = ws;                 ws += 256;
    float* scal    = ws;                 ws += 8;
    float* sqk     = ws;                 ws += 256 * 256;
    float* eqk     = ws;                 ws += 256 * 256;
    float* sqb     = ws;                 ws += 256;
    float* eqb     = ws;                 ws += 256;

    k_pool1<<<1024, 256, 0, stream>>>(ids, emb, pos, partial);

    k_prep<<<1126, 256, 0, stream>>>(pred_w, pred_b, upd_w, upd_b, init_w,
                                     sw, sb, ew, eb, kw, kb, w1, partial,
                                     CM, CMI, KSt, KEt, W1t,
                                     cvec, rc0, vsk, vse, ksb, keb, scal);

    k_init<<<256, 256, 0, stream>>>(partial, CMI, init_b, rA, ff);

    float* cur = rA;
    float* nxt = rB;
    for (int it = 0; it < NITERS; ++it) {
        k_stage<<<512, 256, 0, stream>>>(cur, CM, cvec, rc0, nxt);
        float* tmp = cur; cur = nxt; nxt = tmp;
    }
    // NITERS even -> final reps in rA

    k_heads<<<256, 256, 0, stream>>>(rA, ff, KSt, KEt, ksb, keb, vsk, vse, scal,
                                     W1t, b1, w2, b2, sqk, eqk, sqb, eqb, out);

    k_logits<<<1024, 512, 0, stream>>>(ids, emb, pos, sqk, eqk, sqb, eqb, out);
}